// Round 11
// baseline (1087.072 us; speedup 1.0000x reference)
//
#include <hip/hip_runtime.h>
#include <math.h>

#define G   200
#define G2  40000
#define NPT 128

// float-space constants (match f32 arithmetic of the reference)
__device__ __forceinline__ float f_min_lon() { return 95.987f; }
__device__ __forceinline__ float f_min_lat() { return 31.3039f; }
__device__ __forceinline__ float f_dlon()    { return (float)((109.4132 - 95.987) / 200.0); }
__device__ __forceinline__ float f_dlat()    { return (float)((42.879 - 31.3039) / 200.0); }
__device__ __forceinline__ float f_rad()     { return 0.017453292519943295f; } // pi/180 -> f32

// fast tanh: (e-1)*rcp(e+1), e = exp2(2*log2e*x). ~2-3 ulp vs libm; R5-R10
// proved this flips no discrete decision (absmax 0.0 all rounds).
__device__ __forceinline__ float fast_tanh(float x) {
    float xc = fminf(fmaxf(x, -30.0f), 30.0f);
    float e = __builtin_amdgcn_exp2f(xc * 2.8853900817779268f); // 2*log2(e)
    return (e - 1.0f) * __builtin_amdgcn_rcpf(e + 1.0f);
}

// workspace float layout (after 16-byte header: key @0, done-counter @4)
#define W1A_OFF  0        // 32  : w1[0][k] * a1[k]
#define B2F_OFF  32       // 32  : folded layer-2 bias
#define W2F_OFF  64       // 1024: w2[k][j] * a2[j]
#define W3P_OFF  1088     // 256 : w3 padded [32][8] (cols 5..7 = 0)
#define B3_OFF   1344     // 5 (pad to 8)
#define SW_FLOATS 1352
#define PERN_OFF 1352     // 128*8: {sin(lat2), cos(lat2), lon2rad, tim, rid, pad...}
#define C_OFF    2376     // 128*32: per-n folded layer-1 constant (16B-aligned)
#define SLAT_OFF 6472     // 200: sinf(lat1[gi])
#define CLAT_OFF 6672     // 200: cosf(lat1[gi])
#define SDL_OFF  6872     // 25600*2 interleaved {sinf(dl), cosf(dl)} per (gj,n)
#define WS_FLOATS (6872 + 200*128*2)

__global__ void setup_kernel(const float* __restrict__ x,
                             const float* __restrict__ w1, const float* __restrict__ b1,
                             const float* __restrict__ g1, const float* __restrict__ be1,
                             const float* __restrict__ m1, const float* __restrict__ v1,
                             const float* __restrict__ w2, const float* __restrict__ b2,
                             const float* __restrict__ g2, const float* __restrict__ be2,
                             const float* __restrict__ m2, const float* __restrict__ v2,
                             const float* __restrict__ w3, const float* __restrict__ b3,
                             float* __restrict__ wsf, int has_tab, int has_pq)
{
    const int t = threadIdx.x; // 256 threads
    if (blockIdx.x != 0) {
        if (!has_pq) return;
        int idx = (blockIdx.x - 1) * 256 + t;   // 25600 total
        if (idx >= 200 * NPT) return;
        int gj = idx >> 7, n = idx & 127;
        float lon1 = (f_min_lon() + f_dlon() * (float)gj) * f_rad();
        float lon2 = x[n * 4 + 0] * f_rad();
        float dl = lon2 - lon1;
        wsf[SDL_OFF + idx * 2 + 0] = sinf(dl);
        wsf[SDL_OFF + idx * 2 + 1] = cosf(dl);
        return;
    }
    for (int idx = t; idx < 1024; idx += 256) {
        int j = idx & 31;
        float a2 = g2[j] / sqrtf(v2[j] + 1e-5f);
        wsf[W2F_OFF + idx] = w2[idx] * a2;
    }
    if (t < 32) {
        float a1 = g1[t] / sqrtf(v1[t] + 1e-5f);
        wsf[W1A_OFF + t] = w1[t] * a1;
        float a2 = g2[t] / sqrtf(v2[t] + 1e-5f);
        wsf[B2F_OFF + t] = (b2[t] - m2[t]) * a2 + be2[t];
    }
    {
        int j = t >> 3, c = t & 7;
        wsf[W3P_OFF + t] = (c < 5) ? w3[j * 5 + c] : 0.0f;  // padded copy
    }
    if (t < 8) wsf[B3_OFF + t] = (t < 5) ? b3[t] : 0.0f;
    if (t < NPT) {
        float lon = x[t * 4 + 0], lat = x[t * 4 + 1];
        float tim = x[t * 4 + 2], rid = x[t * 4 + 3];
        float lat2 = lat * f_rad();
        wsf[PERN_OFF + t * 8 + 0] = sinf(lat2);
        wsf[PERN_OFF + t * 8 + 1] = cosf(lat2);
        wsf[PERN_OFF + t * 8 + 2] = lon * f_rad();
        wsf[PERN_OFF + t * 8 + 3] = tim;
        wsf[PERN_OFF + t * 8 + 4] = rid;
        wsf[PERN_OFF + t * 8 + 5] = 0.0f;
        wsf[PERN_OFF + t * 8 + 6] = 0.0f;
        wsf[PERN_OFF + t * 8 + 7] = 0.0f;
    }
    for (int idx = t; idx < NPT * 32; idx += 256) {
        int n = idx >> 5, k = idx & 31;
        float a1 = g1[k] / sqrtf(v1[k] + 1e-5f);
        float tim = x[n * 4 + 2];
        wsf[C_OFF + idx] = ((tim / 100.0f) * w1[32 + k] + b1[k] - m1[k]) * a1 + be1[k];
    }
    if (has_tab && t < 200) {
        float lat1 = (f_min_lat() + f_dlat() * (float)t) * f_rad();
        wsf[SLAT_OFF + t] = sinf(lat1);
        wsf[CLAT_OFF + t] = cosf(lat1);
    }
}

// ---- two grid points (ia, ia+1) for point n, weights from LDS (sw) ----
// EXACT R6 structure (2 chains, VGPR 64, ~3 waves/SIMD, 263 us measured) —
// chains=3,4 all hit the unified-register cliff (R7-R10: spill or 2-wave
// occupancy collapse). Only change vs R6: W3 padded rows -> b128 layer-3
// reads (values + fma order identical).
template<bool TAB, bool PQ>
__device__ __forceinline__ void compute_pair2(int ia, int n, const float* __restrict__ sw,
                                              const float* __restrict__ wsf,
                                              int& pa, int& pb)
{
    const int ib = ia + 1;
    int gia = ia / G, gja = ia - gia * G;
    int gib = ib / G, gjb = ib - gib * G;

    float s1a, c1a, s1b, c1b;
    if (TAB) {
        s1a = wsf[SLAT_OFF + gia]; c1a = wsf[CLAT_OFF + gia];
        s1b = wsf[SLAT_OFF + gib]; c1b = wsf[CLAT_OFF + gib];
    } else {
        float lat1a = (f_min_lat() + f_dlat() * (float)gia) * f_rad();
        float lat1b = (f_min_lat() + f_dlat() * (float)gib) * f_rad();
        s1a = sinf(lat1a); c1a = cosf(lat1a);
        s1b = sinf(lat1b); c1b = cosf(lat1b);
    }

    const float* pn = wsf + PERN_OFF + n * 8;
    float slat2 = pn[0], clat2 = pn[1];

    float sdla, cdla, sdlb, cdlb;
    if (PQ) {
        const float2* T = (const float2*)(wsf + SDL_OFF);
        float2 ta = T[gja * NPT + n];
        float2 tb = T[gjb * NPT + n];
        sdla = ta.x; cdla = ta.y;
        sdlb = tb.x; cdlb = tb.y;
    } else {
        float lon2 = pn[2];
        float lon1a = (f_min_lon() + f_dlon() * (float)gja) * f_rad();
        float lon1b = (f_min_lon() + f_dlon() * (float)gjb) * f_rad();
        float dla = lon2 - lon1a, dlb = lon2 - lon1b;
        sdla = sinf(dla); cdla = cosf(dla);
        sdlb = sinf(dlb); cdlb = cosf(dlb);
    }

    float Aa = clat2 * sdla;
    float Ba = c1a * slat2 - s1a * clat2 * cdla;
    float Ab = clat2 * sdlb;
    float Bb = c1b * slat2 - s1b * clat2 * cdlb;
    float na_ = sqrtf(Aa * Aa + Ba * Ba);
    float nb_ = sqrtf(Ab * Ab + Bb * Bb);
    float da_ = s1a * slat2 + c1a * clat2 * cdla;
    float db_ = s1b * slat2 + c1b * clat2 * cdlb;
    float ua = (atan2f(na_, da_) * 6371.0f) / 100.0f;
    float ub = (atan2f(nb_, db_) * 6371.0f) / 100.0f;

    const float4* W1A4 = (const float4*)(sw + W1A_OFF);
    const float4* C4   = (const float4*)(wsf + C_OFF + n * 32);
    float h1a[32], h1b[32];
#pragma unroll
    for (int q = 0; q < 8; q++) {
        float4 wa = W1A4[q];
        float4 cc = C4[q];
        h1a[4 * q + 0] = fast_tanh(fmaf(ua, wa.x, cc.x));
        h1b[4 * q + 0] = fast_tanh(fmaf(ub, wa.x, cc.x));
        h1a[4 * q + 1] = fast_tanh(fmaf(ua, wa.y, cc.y));
        h1b[4 * q + 1] = fast_tanh(fmaf(ub, wa.y, cc.y));
        h1a[4 * q + 2] = fast_tanh(fmaf(ua, wa.z, cc.z));
        h1b[4 * q + 2] = fast_tanh(fmaf(ub, wa.z, cc.z));
        h1a[4 * q + 3] = fast_tanh(fmaf(ua, wa.w, cc.w));
        h1b[4 * q + 3] = fast_tanh(fmaf(ub, wa.w, cc.w));
    }

    float lga[5], lgb[5];
#pragma unroll
    for (int c = 0; c < 5; c++) { lga[c] = sw[B3_OFF + c]; lgb[c] = sw[B3_OFF + c]; }

#pragma unroll 1
    for (int jc = 0; jc < 4; jc++) {
        float aa[8], ab[8];
        {
            const float4* B2F4 = (const float4*)(sw + B2F_OFF + jc * 8);
            float4 b0 = B2F4[0], b1v = B2F4[1];
            aa[0] = b0.x;  aa[1] = b0.y;  aa[2] = b0.z;  aa[3] = b0.w;
            aa[4] = b1v.x; aa[5] = b1v.y; aa[6] = b1v.z; aa[7] = b1v.w;
            ab[0] = b0.x;  ab[1] = b0.y;  ab[2] = b0.z;  ab[3] = b0.w;
            ab[4] = b1v.x; ab[5] = b1v.y; ab[6] = b1v.z; ab[7] = b1v.w;
        }
        const float* wbase = sw + W2F_OFF + jc * 8;
#pragma unroll
        for (int k = 0; k < 32; k++) {
            const float4* W24 = (const float4*)(wbase + k * 32);
            float4 w0 = W24[0], w1v = W24[1];
            float hka = h1a[k], hkb = h1b[k];
            aa[0] = fmaf(hka, w0.x,  aa[0]);  ab[0] = fmaf(hkb, w0.x,  ab[0]);
            aa[1] = fmaf(hka, w0.y,  aa[1]);  ab[1] = fmaf(hkb, w0.y,  ab[1]);
            aa[2] = fmaf(hka, w0.z,  aa[2]);  ab[2] = fmaf(hkb, w0.z,  ab[2]);
            aa[3] = fmaf(hka, w0.w,  aa[3]);  ab[3] = fmaf(hkb, w0.w,  ab[3]);
            aa[4] = fmaf(hka, w1v.x, aa[4]);  ab[4] = fmaf(hkb, w1v.x, ab[4]);
            aa[5] = fmaf(hka, w1v.y, aa[5]);  ab[5] = fmaf(hkb, w1v.y, ab[5]);
            aa[6] = fmaf(hka, w1v.z, aa[6]);  ab[6] = fmaf(hkb, w1v.z, ab[6]);
            aa[7] = fmaf(hka, w1v.w, aa[7]);  ab[7] = fmaf(hkb, w1v.w, ab[7]);
        }
#pragma unroll
        for (int m = 0; m < 8; m++) {
            int j = jc * 8 + m;
            const float4* W3P4 = (const float4*)(sw + W3P_OFF + j * 8);
            float4 wa = W3P4[0];
            float  w4 = sw[W3P_OFF + j * 8 + 4];
            float h2a = fast_tanh(aa[m]);
            float h2b = fast_tanh(ab[m]);
            lga[0] = fmaf(h2a, wa.x, lga[0]);  lgb[0] = fmaf(h2b, wa.x, lgb[0]);
            lga[1] = fmaf(h2a, wa.y, lga[1]);  lgb[1] = fmaf(h2b, wa.y, lgb[1]);
            lga[2] = fmaf(h2a, wa.z, lga[2]);  lgb[2] = fmaf(h2b, wa.z, lgb[2]);
            lga[3] = fmaf(h2a, wa.w, lga[3]);  lgb[3] = fmaf(h2b, wa.w, lgb[3]);
            lga[4] = fmaf(h2a, w4,   lga[4]);  lgb[4] = fmaf(h2b, w4,   lgb[4]);
        }
    }

    int ba = 0; float va = lga[0];
    int bb = 0; float vb = lgb[0];
#pragma unroll
    for (int c = 1; c < 5; c++) {
        if (lga[c] > va) { va = lga[c]; ba = c; }
        if (lgb[c] > vb) { vb = lgb[c]; bb = c; }
    }
    pa = ba; pb = bb;
}

// single-pair path (winner finalize) — identical math, weights from LDS sw.
template<bool TAB, bool PQ>
__device__ __forceinline__ void compute_pair_sw(int i, int n,
                                                const float* __restrict__ sw,
                                                const float* __restrict__ wsf,
                                                int& pid, float& gd_out)
{
    int gi = i / G;
    int gj = i - gi * G;

    float s1, c1;
    if (TAB) {
        s1 = wsf[SLAT_OFF + gi]; c1 = wsf[CLAT_OFF + gi];
    } else {
        float lat1 = (f_min_lat() + f_dlat() * (float)gi) * f_rad();
        s1 = sinf(lat1); c1 = cosf(lat1);
    }

    const float* pn = wsf + PERN_OFF + n * 8;
    float slat2 = pn[0], clat2 = pn[1];

    float sdl, cdl;
    if (PQ) {
        const float2* T = (const float2*)(wsf + SDL_OFF);
        float2 tv = T[gj * NPT + n];
        sdl = tv.x; cdl = tv.y;
    } else {
        float lon2 = pn[2];
        float lon1 = (f_min_lon() + f_dlon() * (float)gj) * f_rad();
        float dl = lon2 - lon1;
        sdl = sinf(dl); cdl = cosf(dl);
    }

    float A = clat2 * sdl;
    float B = c1 * slat2 - s1 * clat2 * cdl;
    float numer = sqrtf(A * A + B * B);
    float denom = s1 * slat2 + c1 * clat2 * cdl;
    float gd = atan2f(numer, denom) * 6371.0f;
    float u = gd / 100.0f;

    const float4* W1A4 = (const float4*)(sw + W1A_OFF);
    const float4* C4   = (const float4*)(wsf + C_OFF + n * 32);
    float h1[32];
#pragma unroll
    for (int q = 0; q < 8; q++) {
        float4 wa = W1A4[q];
        float4 cc = C4[q];
        h1[4 * q + 0] = fast_tanh(fmaf(u, wa.x, cc.x));
        h1[4 * q + 1] = fast_tanh(fmaf(u, wa.y, cc.y));
        h1[4 * q + 2] = fast_tanh(fmaf(u, wa.z, cc.z));
        h1[4 * q + 3] = fast_tanh(fmaf(u, wa.w, cc.w));
    }

    float lg[5];
#pragma unroll
    for (int c = 0; c < 5; c++) lg[c] = sw[B3_OFF + c];

#pragma unroll 1
    for (int jc = 0; jc < 4; jc++) {
        float acc[8];
        {
            const float4* B2F4 = (const float4*)(sw + B2F_OFF + jc * 8);
            float4 b0 = B2F4[0], b1v = B2F4[1];
            acc[0] = b0.x;  acc[1] = b0.y;  acc[2] = b0.z;  acc[3] = b0.w;
            acc[4] = b1v.x; acc[5] = b1v.y; acc[6] = b1v.z; acc[7] = b1v.w;
        }
        const float* wbase = sw + W2F_OFF + jc * 8;
#pragma unroll
        for (int k = 0; k < 32; k++) {
            const float4* W24 = (const float4*)(wbase + k * 32);
            float4 w0 = W24[0], w1v = W24[1];
            float hk = h1[k];
            acc[0] = fmaf(hk, w0.x,  acc[0]);
            acc[1] = fmaf(hk, w0.y,  acc[1]);
            acc[2] = fmaf(hk, w0.z,  acc[2]);
            acc[3] = fmaf(hk, w0.w,  acc[3]);
            acc[4] = fmaf(hk, w1v.x, acc[4]);
            acc[5] = fmaf(hk, w1v.y, acc[5]);
            acc[6] = fmaf(hk, w1v.z, acc[6]);
            acc[7] = fmaf(hk, w1v.w, acc[7]);
        }
#pragma unroll
        for (int m = 0; m < 8; m++) {
            int j = jc * 8 + m;
            float h2 = fast_tanh(acc[m]);
            const float4* W3P4 = (const float4*)(sw + W3P_OFF + j * 8);
            float4 wa = W3P4[0];
            float  w4 = sw[W3P_OFF + j * 8 + 4];
            lg[0] = fmaf(h2, wa.x, lg[0]);
            lg[1] = fmaf(h2, wa.y, lg[1]);
            lg[2] = fmaf(h2, wa.z, lg[2]);
            lg[3] = fmaf(h2, wa.w, lg[3]);
            lg[4] = fmaf(h2, w4,   lg[4]);
        }
    }

    int best = 0;
    float bv = lg[0];
#pragma unroll
    for (int c = 1; c < 5; c++)
        if (lg[c] > bv) { bv = lg[c]; best = c; }
    pid = best;
    gd_out = gd;
}

// R6 shell: 256 threads, (256,2), 4 grid points/block, 10000 blocks.
// Fused last-block finalize (R10-proven) replaces the pass2 launch.
template<bool TAB, bool PQ>
__global__ __launch_bounds__(256, 2) void pass1_kernel(const float* __restrict__ wsf,
                                                       unsigned* __restrict__ key,
                                                       unsigned* __restrict__ done,
                                                       float* __restrict__ out)
{
    __shared__ float sw[SW_FLOATS];
    __shared__ int sa[4], sb[4];
    __shared__ unsigned s_key;
    __shared__ int s_last;
    const int t = threadIdx.x;
    for (int idx = t; idx < SW_FLOATS; idx += 256) sw[idx] = wsf[idx];
    __syncthreads();

    const int n = t & 127;
    const int h = t >> 7;            // waves 0,1 -> h=0 ; waves 2,3 -> h=1
    const int base = blockIdx.x * 4;
    const int ia = base + h * 2;

    int pa, pb;
    compute_pair2<TAB, PQ>(ia, n, sw, wsf, pa, pb);

    float rid = wsf[PERN_OFF + n * 8 + 4];
    unsigned long long ba_ = __ballot((float)pa == rid);
    unsigned long long bb_ = __ballot((float)pb == rid);
    if ((t & 63) == 0) {
        sa[t >> 6] = __popcll(ba_);
        sb[t >> 6] = __popcll(bb_);
    }
    __syncthreads();
    if (t == 0) {
        int n0 = sa[0] + sa[1];   // i = base+0
        int n1 = sb[0] + sb[1];   // i = base+1
        int n2 = sa[2] + sa[3];   // i = base+2
        int n3 = sb[2] + sb[3];   // i = base+3
        unsigned k0 = ((unsigned)n0 << 16) | (unsigned)(G2 - 1 - (base + 0));
        unsigned k1 = ((unsigned)n1 << 16) | (unsigned)(G2 - 1 - (base + 1));
        unsigned k2 = ((unsigned)n2 << 16) | (unsigned)(G2 - 1 - (base + 2));
        unsigned k3 = ((unsigned)n3 << 16) | (unsigned)(G2 - 1 - (base + 3));
        unsigned km = max(max(k0, k1), max(k2, k3));
        atomicMax(key, km);
    }

    // ---- last-block finalize (replaces pass2 kernel; R10-proven) ----
    __threadfence();
    if (t == 0) {
        unsigned old = atomicAdd(done, 1u);
        s_last = (old == (unsigned)(gridDim.x - 1));
        if (s_last) s_key = atomicAdd(key, 0u);   // device-scope read of final max
    }
    __syncthreads();
    if (!s_last) return;

    unsigned kfin = s_key;
    int iwin = (G2 - 1) - (int)(kfin & 0xFFFFu);
    int num  = (int)(kfin >> 16);
    if (t < NPT) {
        int pw; float gd;
        compute_pair_sw<TAB, PQ>(iwin, t, sw, wsf, pw, gd);
        out[t] = (float)pw;                               // class_
        float tim = wsf[PERN_OFF + t * 8 + 3];
        out[NPT + 2 * t + 0] = (gd / 100.0f) * 100.0f;    // ph[:,0]
        out[NPT + 2 * t + 1] = (tim / 100.0f) * 100.0f;   // ph[:,1]
        if (t == 0) {
            out[3 * NPT] = (float)num;                    // max(num)
            int gi = iwin / G, gj = iwin - gi * G;
            out[3 * NPT + 1] = f_min_lon() + f_dlon() * (float)gj;
            out[3 * NPT + 2] = f_min_lat() + f_dlat() * (float)gi;
        }
    }
}

extern "C" void kernel_launch(void* const* d_in, const int* in_sizes, int n_in,
                              void* d_out, int out_size, void* d_ws, size_t ws_size,
                              hipStream_t stream)
{
    const float* x   = (const float*)d_in[0];
    const float* w1  = (const float*)d_in[1];
    const float* b1  = (const float*)d_in[2];
    const float* g1  = (const float*)d_in[3];
    const float* be1 = (const float*)d_in[4];
    const float* m1  = (const float*)d_in[5];
    const float* v1  = (const float*)d_in[6];
    const float* w2  = (const float*)d_in[7];
    const float* b2  = (const float*)d_in[8];
    const float* g2  = (const float*)d_in[9];
    const float* be2 = (const float*)d_in[10];
    const float* m2  = (const float*)d_in[11];
    const float* v2  = (const float*)d_in[12];
    const float* w3  = (const float*)d_in[13];
    const float* b3  = (const float*)d_in[14];

    unsigned* key  = (unsigned*)d_ws;
    unsigned* done = (unsigned*)((char*)d_ws + 4);
    float* wsf = (float*)((char*)d_ws + 16);
    float* out = (float*)d_out;

    const size_t need_tab = 16 + 4ull * (CLAT_OFF + 200);
    const size_t need_pq  = 16 + 4ull * WS_FLOATS;
    const bool tab = ws_size >= need_tab;
    const bool pq  = ws_size >= need_pq;

    hipMemsetAsync(d_ws, 0, 16, stream);
    setup_kernel<<<pq ? 101 : 1, 256, 0, stream>>>(x, w1, b1, g1, be1, m1, v1,
                                                   w2, b2, g2, be2, m2, v2, w3, b3, wsf,
                                                   tab ? 1 : 0, pq ? 1 : 0);
    if (pq) {
        pass1_kernel<true, true><<<G2 / 4, 256, 0, stream>>>(wsf, key, done, out);
    } else if (tab) {
        pass1_kernel<true, false><<<G2 / 4, 256, 0, stream>>>(wsf, key, done, out);
    } else {
        pass1_kernel<false, false><<<G2 / 4, 256, 0, stream>>>(wsf, key, done, out);
    }
}

// Round 12
// 334.587 us; speedup vs baseline: 3.2490x; 3.2490x over previous
//
#include <hip/hip_runtime.h>
#include <math.h>

#define G   200
#define G2  40000
#define NPT 128

// float-space constants (match f32 arithmetic of the reference)
__device__ __forceinline__ float f_min_lon() { return 95.987f; }
__device__ __forceinline__ float f_min_lat() { return 31.3039f; }
__device__ __forceinline__ float f_dlon()    { return (float)((109.4132 - 95.987) / 200.0); }
__device__ __forceinline__ float f_dlat()    { return (float)((42.879 - 31.3039) / 200.0); }
__device__ __forceinline__ float f_rad()     { return 0.017453292519943295f; } // pi/180 -> f32

// fast tanh: (e-1)*rcp(e+1), e = exp2(2*log2e*x). ~2-3 ulp vs libm; R5-R11
// proved this flips no discrete decision (absmax 0.0 all rounds).
__device__ __forceinline__ float fast_tanh(float x) {
    float xc = fminf(fmaxf(x, -30.0f), 30.0f);
    float e = __builtin_amdgcn_exp2f(xc * 2.8853900817779268f); // 2*log2(e)
    return (e - 1.0f) * __builtin_amdgcn_rcpf(e + 1.0f);
}

// workspace float layout (after 16-byte header holding the atomic key)
#define W1A_OFF  0        // 32  : w1[0][k] * a1[k]
#define B2F_OFF  32       // 32  : folded layer-2 bias
#define W2F_OFF  64       // 1024: w2[k][j] * a2[j]
#define W3P_OFF  1088     // 256 : w3 padded [32][8] (cols 5..7 = 0)
#define B3_OFF   1344     // 5 (pad to 8)
#define PERN_OFF 1352     // 128*8: {sin(lat2), cos(lat2), lon2rad, tim, rid, pad...}
#define C_OFF    2376     // 128*32: per-n folded layer-1 constant (16B-aligned)
#define SLAT_OFF 6472     // 200: sinf(lat1[gi])
#define CLAT_OFF 6672     // 200: cosf(lat1[gi])
#define SDL_OFF  6872     // 25600*2 interleaved {sinf(dl), cosf(dl)} per (gj,n)
#define WS_FLOATS (6872 + 200*128*2)

__global__ void setup_kernel(const float* __restrict__ x,
                             const float* __restrict__ w1, const float* __restrict__ b1,
                             const float* __restrict__ g1, const float* __restrict__ be1,
                             const float* __restrict__ m1, const float* __restrict__ v1,
                             const float* __restrict__ w2, const float* __restrict__ b2,
                             const float* __restrict__ g2, const float* __restrict__ be2,
                             const float* __restrict__ m2, const float* __restrict__ v2,
                             const float* __restrict__ w3, const float* __restrict__ b3,
                             float* __restrict__ wsf, int has_tab, int has_pq)
{
    const int t = threadIdx.x; // 256 threads
    if (blockIdx.x != 0) {
        if (!has_pq) return;
        int idx = (blockIdx.x - 1) * 256 + t;   // 25600 total
        if (idx >= 200 * NPT) return;
        int gj = idx >> 7, n = idx & 127;
        float lon1 = (f_min_lon() + f_dlon() * (float)gj) * f_rad();
        float lon2 = x[n * 4 + 0] * f_rad();
        float dl = lon2 - lon1;
        wsf[SDL_OFF + idx * 2 + 0] = sinf(dl);
        wsf[SDL_OFF + idx * 2 + 1] = cosf(dl);
        return;
    }
    for (int idx = t; idx < 1024; idx += 256) {
        int j = idx & 31;
        float a2 = g2[j] / sqrtf(v2[j] + 1e-5f);
        wsf[W2F_OFF + idx] = w2[idx] * a2;
    }
    if (t < 32) {
        float a1 = g1[t] / sqrtf(v1[t] + 1e-5f);
        wsf[W1A_OFF + t] = w1[t] * a1;
        float a2 = g2[t] / sqrtf(v2[t] + 1e-5f);
        wsf[B2F_OFF + t] = (b2[t] - m2[t]) * a2 + be2[t];
    }
    {
        int j = t >> 3, c = t & 7;
        wsf[W3P_OFF + t] = (c < 5) ? w3[j * 5 + c] : 0.0f;  // padded copy
    }
    if (t < 8) wsf[B3_OFF + t] = (t < 5) ? b3[t] : 0.0f;
    if (t < NPT) {
        float lon = x[t * 4 + 0], lat = x[t * 4 + 1];
        float tim = x[t * 4 + 2], rid = x[t * 4 + 3];
        float lat2 = lat * f_rad();
        wsf[PERN_OFF + t * 8 + 0] = sinf(lat2);
        wsf[PERN_OFF + t * 8 + 1] = cosf(lat2);
        wsf[PERN_OFF + t * 8 + 2] = lon * f_rad();
        wsf[PERN_OFF + t * 8 + 3] = tim;
        wsf[PERN_OFF + t * 8 + 4] = rid;
        wsf[PERN_OFF + t * 8 + 5] = 0.0f;
        wsf[PERN_OFF + t * 8 + 6] = 0.0f;
        wsf[PERN_OFF + t * 8 + 7] = 0.0f;
    }
    for (int idx = t; idx < NPT * 32; idx += 256) {
        int n = idx >> 5, k = idx & 31;
        float a1 = g1[k] / sqrtf(v1[k] + 1e-5f);
        float tim = x[n * 4 + 2];
        wsf[C_OFF + idx] = ((tim / 100.0f) * w1[32 + k] + b1[k] - m1[k]) * a1 + be1[k];
    }
    if (has_tab && t < 200) {
        float lat1 = (f_min_lat() + f_dlat() * (float)t) * f_rad();
        wsf[SLAT_OFF + t] = sinf(lat1);
        wsf[CLAT_OFF + t] = cosf(lat1);
    }
}

// ---- two grid points (ia, ia+1) for point n ----
// R6 compute structure (2 chains — chains=3,4 hit the register cliff,
// R7-R10). NO LDS staging: all weight indices are wave-uniform, so weight
// reads compile to s_load into SGPRs (scalar cache; R2 evidence:
// SGPR_Count=112 with this pattern). v_fma reads the weight as its one
// allowed SGPR operand -> LDS pipe (R6's pole, ~270 us) goes to ~0.
template<bool TAB, bool PQ>
__device__ __forceinline__ void compute_pair2(int ia, int n,
                                              const float* __restrict__ wsf,
                                              int& pa, int& pb)
{
    const int ib = ia + 1;
    int gia = ia / G, gja = ia - gia * G;
    int gib = ib / G, gjb = ib - gib * G;

    float s1a, c1a, s1b, c1b;
    if (TAB) {
        s1a = wsf[SLAT_OFF + gia]; c1a = wsf[CLAT_OFF + gia];
        s1b = wsf[SLAT_OFF + gib]; c1b = wsf[CLAT_OFF + gib];
    } else {
        float lat1a = (f_min_lat() + f_dlat() * (float)gia) * f_rad();
        float lat1b = (f_min_lat() + f_dlat() * (float)gib) * f_rad();
        s1a = sinf(lat1a); c1a = cosf(lat1a);
        s1b = sinf(lat1b); c1b = cosf(lat1b);
    }

    const float* pn = wsf + PERN_OFF + n * 8;
    float slat2 = pn[0], clat2 = pn[1];

    float sdla, cdla, sdlb, cdlb;
    if (PQ) {
        const float2* T = (const float2*)(wsf + SDL_OFF);
        float2 ta = T[gja * NPT + n];
        float2 tb = T[gjb * NPT + n];
        sdla = ta.x; cdla = ta.y;
        sdlb = tb.x; cdlb = tb.y;
    } else {
        float lon2 = pn[2];
        float lon1a = (f_min_lon() + f_dlon() * (float)gja) * f_rad();
        float lon1b = (f_min_lon() + f_dlon() * (float)gjb) * f_rad();
        float dla = lon2 - lon1a, dlb = lon2 - lon1b;
        sdla = sinf(dla); cdla = cosf(dla);
        sdlb = sinf(dlb); cdlb = cosf(dlb);
    }

    float Aa = clat2 * sdla;
    float Ba = c1a * slat2 - s1a * clat2 * cdla;
    float Ab = clat2 * sdlb;
    float Bb = c1b * slat2 - s1b * clat2 * cdlb;
    float na_ = sqrtf(Aa * Aa + Ba * Ba);
    float nb_ = sqrtf(Ab * Ab + Bb * Bb);
    float da_ = s1a * slat2 + c1a * clat2 * cdla;
    float db_ = s1b * slat2 + c1b * clat2 * cdlb;
    float ua = (atan2f(na_, da_) * 6371.0f) / 100.0f;
    float ub = (atan2f(nb_, db_) * 6371.0f) / 100.0f;

    const float4* W1A4 = (const float4*)(wsf + W1A_OFF);
    const float4* C4   = (const float4*)(wsf + C_OFF + n * 32);
    float h1a[32], h1b[32];
#pragma unroll
    for (int q = 0; q < 8; q++) {
        float4 wa = W1A4[q];
        float4 cc = C4[q];
        h1a[4 * q + 0] = fast_tanh(fmaf(ua, wa.x, cc.x));
        h1b[4 * q + 0] = fast_tanh(fmaf(ub, wa.x, cc.x));
        h1a[4 * q + 1] = fast_tanh(fmaf(ua, wa.y, cc.y));
        h1b[4 * q + 1] = fast_tanh(fmaf(ub, wa.y, cc.y));
        h1a[4 * q + 2] = fast_tanh(fmaf(ua, wa.z, cc.z));
        h1b[4 * q + 2] = fast_tanh(fmaf(ub, wa.z, cc.z));
        h1a[4 * q + 3] = fast_tanh(fmaf(ua, wa.w, cc.w));
        h1b[4 * q + 3] = fast_tanh(fmaf(ub, wa.w, cc.w));
    }

    float lga[5], lgb[5];
#pragma unroll
    for (int c = 0; c < 5; c++) { lga[c] = wsf[B3_OFF + c]; lgb[c] = wsf[B3_OFF + c]; }

#pragma unroll 1
    for (int jc = 0; jc < 4; jc++) {
        float aa[8], ab[8];
        {
            const float4* B2F4 = (const float4*)(wsf + B2F_OFF + jc * 8);
            float4 b0 = B2F4[0], b1v = B2F4[1];
            aa[0] = b0.x;  aa[1] = b0.y;  aa[2] = b0.z;  aa[3] = b0.w;
            aa[4] = b1v.x; aa[5] = b1v.y; aa[6] = b1v.z; aa[7] = b1v.w;
            ab[0] = b0.x;  ab[1] = b0.y;  ab[2] = b0.z;  ab[3] = b0.w;
            ab[4] = b1v.x; ab[5] = b1v.y; ab[6] = b1v.z; ab[7] = b1v.w;
        }
        const float* wbase = wsf + W2F_OFF + jc * 8;
#pragma unroll
        for (int k = 0; k < 32; k++) {
            const float4* W24 = (const float4*)(wbase + k * 32);
            float4 w0 = W24[0], w1v = W24[1];
            float hka = h1a[k], hkb = h1b[k];
            aa[0] = fmaf(hka, w0.x,  aa[0]);  ab[0] = fmaf(hkb, w0.x,  ab[0]);
            aa[1] = fmaf(hka, w0.y,  aa[1]);  ab[1] = fmaf(hkb, w0.y,  ab[1]);
            aa[2] = fmaf(hka, w0.z,  aa[2]);  ab[2] = fmaf(hkb, w0.z,  ab[2]);
            aa[3] = fmaf(hka, w0.w,  aa[3]);  ab[3] = fmaf(hkb, w0.w,  ab[3]);
            aa[4] = fmaf(hka, w1v.x, aa[4]);  ab[4] = fmaf(hkb, w1v.x, ab[4]);
            aa[5] = fmaf(hka, w1v.y, aa[5]);  ab[5] = fmaf(hkb, w1v.y, ab[5]);
            aa[6] = fmaf(hka, w1v.z, aa[6]);  ab[6] = fmaf(hkb, w1v.z, ab[6]);
            aa[7] = fmaf(hka, w1v.w, aa[7]);  ab[7] = fmaf(hkb, w1v.w, ab[7]);
        }
#pragma unroll
        for (int m = 0; m < 8; m++) {
            int j = jc * 8 + m;
            const float4* W3P4 = (const float4*)(wsf + W3P_OFF + j * 8);
            float4 wa = W3P4[0];
            float  w4 = wsf[W3P_OFF + j * 8 + 4];
            float h2a = fast_tanh(aa[m]);
            float h2b = fast_tanh(ab[m]);
            lga[0] = fmaf(h2a, wa.x, lga[0]);  lgb[0] = fmaf(h2b, wa.x, lgb[0]);
            lga[1] = fmaf(h2a, wa.y, lga[1]);  lgb[1] = fmaf(h2b, wa.y, lgb[1]);
            lga[2] = fmaf(h2a, wa.z, lga[2]);  lgb[2] = fmaf(h2b, wa.z, lgb[2]);
            lga[3] = fmaf(h2a, wa.w, lga[3]);  lgb[3] = fmaf(h2b, wa.w, lgb[3]);
            lga[4] = fmaf(h2a, w4,   lga[4]);  lgb[4] = fmaf(h2b, w4,   lgb[4]);
        }
    }

    int ba = 0; float va = lga[0];
    int bb = 0; float vb = lgb[0];
#pragma unroll
    for (int c = 1; c < 5; c++) {
        if (lga[c] > va) { va = lga[c]; ba = c; }
        if (lgb[c] > vb) { vb = lgb[c]; bb = c; }
    }
    pa = ba; pb = bb;
}

// No LDS staging, no fence, no fused finalize (R11: per-block __threadfence
// collapsed VALUBusy 112%->24% — never again on a wide grid).
template<bool TAB, bool PQ>
__global__ __launch_bounds__(256, 2) void pass1_kernel(const float* __restrict__ wsf,
                                                       unsigned* __restrict__ key)
{
    __shared__ int sa[4], sb[4];
    const int t = threadIdx.x;
    const int n = t & 127;
    const int h = t >> 7;            // waves 0,1 -> h=0 ; waves 2,3 -> h=1
    const int base = blockIdx.x * 4;
    const int ia = base + h * 2;

    int pa, pb;
    compute_pair2<TAB, PQ>(ia, n, wsf, pa, pb);

    float rid = wsf[PERN_OFF + n * 8 + 4];
    unsigned long long ba_ = __ballot((float)pa == rid);
    unsigned long long bb_ = __ballot((float)pb == rid);
    if ((t & 63) == 0) {
        sa[t >> 6] = __popcll(ba_);
        sb[t >> 6] = __popcll(bb_);
    }
    __syncthreads();
    if (t == 0) {
        int n0 = sa[0] + sa[1];   // i = base+0
        int n1 = sb[0] + sb[1];   // i = base+1
        int n2 = sa[2] + sa[3];   // i = base+2
        int n3 = sb[2] + sb[3];   // i = base+3
        unsigned k0 = ((unsigned)n0 << 16) | (unsigned)(G2 - 1 - (base + 0));
        unsigned k1 = ((unsigned)n1 << 16) | (unsigned)(G2 - 1 - (base + 1));
        unsigned k2 = ((unsigned)n2 << 16) | (unsigned)(G2 - 1 - (base + 2));
        unsigned k3 = ((unsigned)n3 << 16) | (unsigned)(G2 - 1 - (base + 3));
        unsigned km = max(max(k0, k1), max(k2, k3));
        atomicMax(key, km);
    }
}

// single-pair version for pass2 (1 block) — identical math path to pass1.
template<bool TAB, bool PQ>
__device__ __forceinline__ void compute_pair(int i, int n, const float* __restrict__ wsf,
                                             int& pid, float& gd_out)
{
    int gi = i / G;
    int gj = i - gi * G;

    float s1, c1;
    if (TAB) {
        s1 = wsf[SLAT_OFF + gi]; c1 = wsf[CLAT_OFF + gi];
    } else {
        float lat1 = (f_min_lat() + f_dlat() * (float)gi) * f_rad();
        s1 = sinf(lat1); c1 = cosf(lat1);
    }

    const float* pn = wsf + PERN_OFF + n * 8;
    float slat2 = pn[0], clat2 = pn[1];

    float sdl, cdl;
    if (PQ) {
        const float2* T = (const float2*)(wsf + SDL_OFF);
        float2 tv = T[gj * NPT + n];
        sdl = tv.x; cdl = tv.y;
    } else {
        float lon2 = pn[2];
        float lon1 = (f_min_lon() + f_dlon() * (float)gj) * f_rad();
        float dl = lon2 - lon1;
        sdl = sinf(dl); cdl = cosf(dl);
    }

    float A = clat2 * sdl;
    float B = c1 * slat2 - s1 * clat2 * cdl;
    float numer = sqrtf(A * A + B * B);
    float denom = s1 * slat2 + c1 * clat2 * cdl;
    float gd = atan2f(numer, denom) * 6371.0f;
    float u = gd / 100.0f;

    const float4* W1A4 = (const float4*)(wsf + W1A_OFF);
    const float4* C4   = (const float4*)(wsf + C_OFF + n * 32);
    float h1[32];
#pragma unroll
    for (int q = 0; q < 8; q++) {
        float4 wa = W1A4[q];
        float4 cc = C4[q];
        h1[4 * q + 0] = fast_tanh(fmaf(u, wa.x, cc.x));
        h1[4 * q + 1] = fast_tanh(fmaf(u, wa.y, cc.y));
        h1[4 * q + 2] = fast_tanh(fmaf(u, wa.z, cc.z));
        h1[4 * q + 3] = fast_tanh(fmaf(u, wa.w, cc.w));
    }

    float lg[5];
#pragma unroll
    for (int c = 0; c < 5; c++) lg[c] = wsf[B3_OFF + c];

#pragma unroll 1
    for (int jc = 0; jc < 4; jc++) {
        float acc[8];
        {
            const float4* B2F4 = (const float4*)(wsf + B2F_OFF + jc * 8);
            float4 b0 = B2F4[0], b1v = B2F4[1];
            acc[0] = b0.x;  acc[1] = b0.y;  acc[2] = b0.z;  acc[3] = b0.w;
            acc[4] = b1v.x; acc[5] = b1v.y; acc[6] = b1v.z; acc[7] = b1v.w;
        }
        const float* wbase = wsf + W2F_OFF + jc * 8;
#pragma unroll
        for (int k = 0; k < 32; k++) {
            const float4* W24 = (const float4*)(wbase + k * 32);
            float4 w0 = W24[0], w1v = W24[1];
            float hk = h1[k];
            acc[0] = fmaf(hk, w0.x,  acc[0]);
            acc[1] = fmaf(hk, w0.y,  acc[1]);
            acc[2] = fmaf(hk, w0.z,  acc[2]);
            acc[3] = fmaf(hk, w0.w,  acc[3]);
            acc[4] = fmaf(hk, w1v.x, acc[4]);
            acc[5] = fmaf(hk, w1v.y, acc[5]);
            acc[6] = fmaf(hk, w1v.z, acc[6]);
            acc[7] = fmaf(hk, w1v.w, acc[7]);
        }
#pragma unroll
        for (int m = 0; m < 8; m++) {
            int j = jc * 8 + m;
            float h2 = fast_tanh(acc[m]);
            const float4* W3P4 = (const float4*)(wsf + W3P_OFF + j * 8);
            float4 wa = W3P4[0];
            float  w4 = wsf[W3P_OFF + j * 8 + 4];
            lg[0] = fmaf(h2, wa.x, lg[0]);
            lg[1] = fmaf(h2, wa.y, lg[1]);
            lg[2] = fmaf(h2, wa.z, lg[2]);
            lg[3] = fmaf(h2, wa.w, lg[3]);
            lg[4] = fmaf(h2, w4,   lg[4]);
        }
    }

    int best = 0;
    float bv = lg[0];
#pragma unroll
    for (int c = 1; c < 5; c++)
        if (lg[c] > bv) { bv = lg[c]; best = c; }
    pid = best;
    gd_out = gd;
}

template<bool TAB, bool PQ>
__global__ __launch_bounds__(NPT) void pass2_kernel(const float* __restrict__ wsf,
                                                    const unsigned* __restrict__ key,
                                                    float* __restrict__ out)
{
    unsigned k = *key;
    int i = (G2 - 1) - (int)(k & 0xFFFFu);
    int num = (int)(k >> 16);
    const int n = threadIdx.x;
    int pid; float gd;
    compute_pair<TAB, PQ>(i, n, wsf, pid, gd);
    out[n] = (float)pid;                                  // class_
    float tim = wsf[PERN_OFF + n * 8 + 3];
    out[NPT + 2 * n + 0] = (gd / 100.0f) * 100.0f;        // ph[:,0]
    out[NPT + 2 * n + 1] = (tim / 100.0f) * 100.0f;       // ph[:,1]
    if (n == 0) {
        out[3 * NPT] = (float)num;                        // max(num)
        int gi = i / G, gj = i - gi * G;
        out[3 * NPT + 1] = f_min_lon() + f_dlon() * (float)gj;  // pos lon
        out[3 * NPT + 2] = f_min_lat() + f_dlat() * (float)gi;  // pos lat
    }
}

extern "C" void kernel_launch(void* const* d_in, const int* in_sizes, int n_in,
                              void* d_out, int out_size, void* d_ws, size_t ws_size,
                              hipStream_t stream)
{
    const float* x   = (const float*)d_in[0];
    const float* w1  = (const float*)d_in[1];
    const float* b1  = (const float*)d_in[2];
    const float* g1  = (const float*)d_in[3];
    const float* be1 = (const float*)d_in[4];
    const float* m1  = (const float*)d_in[5];
    const float* v1  = (const float*)d_in[6];
    const float* w2  = (const float*)d_in[7];
    const float* b2  = (const float*)d_in[8];
    const float* g2  = (const float*)d_in[9];
    const float* be2 = (const float*)d_in[10];
    const float* m2  = (const float*)d_in[11];
    const float* v2  = (const float*)d_in[12];
    const float* w3  = (const float*)d_in[13];
    const float* b3  = (const float*)d_in[14];

    unsigned* key = (unsigned*)d_ws;
    float* wsf = (float*)((char*)d_ws + 16);

    const size_t need_tab = 16 + 4ull * (CLAT_OFF + 200);
    const size_t need_pq  = 16 + 4ull * WS_FLOATS;
    const bool tab = ws_size >= need_tab;
    const bool pq  = ws_size >= need_pq;

    hipMemsetAsync(d_ws, 0, 16, stream);
    setup_kernel<<<pq ? 101 : 1, 256, 0, stream>>>(x, w1, b1, g1, be1, m1, v1,
                                                   w2, b2, g2, be2, m2, v2, w3, b3, wsf,
                                                   tab ? 1 : 0, pq ? 1 : 0);
    if (pq) {
        pass1_kernel<true, true><<<G2 / 4, 256, 0, stream>>>(wsf, key);
        pass2_kernel<true, true><<<1, NPT, 0, stream>>>(wsf, key, (float*)d_out);
    } else if (tab) {
        pass1_kernel<true, false><<<G2 / 4, 256, 0, stream>>>(wsf, key);
        pass2_kernel<true, false><<<1, NPT, 0, stream>>>(wsf, key, (float*)d_out);
    } else {
        pass1_kernel<false, false><<<G2 / 4, 256, 0, stream>>>(wsf, key);
        pass2_kernel<false, false><<<1, NPT, 0, stream>>>(wsf, key, (float*)d_out);
    }
}